// Round 4
// baseline (473.645 us; speedup 1.0000x reference)
//
#include <hip/hip_runtime.h>
#include <stdint.h>

// Problem constants
#define F_     128
#define N_     12288
#define NH_    9
#define NSLOT_ 8
#define NVARS_ 8
#define NUP_   (4*N_)
#define K6_    (NH_*F_)   // 1152
#define NSTEP6 (K6_/64)   // 18

typedef __attribute__((ext_vector_type(8))) short bf16x8;
typedef __attribute__((ext_vector_type(4))) float f32x4;

typedef const __attribute__((address_space(1))) unsigned char* gp1_t;
typedef __attribute__((address_space(3))) unsigned char* lp3_t;

__device__ __forceinline__ void load16(const void* g, void* l) {
  __builtin_amdgcn_global_load_lds((gp1_t)g, (lp3_t)l, 16, 0, 0);
}

__device__ __forceinline__ unsigned short f2bf(float f) {
  union { float f; unsigned int u; } x; x.f = f;
  unsigned int u = x.u;
  unsigned int r = u + 0x7FFFu + ((u >> 16) & 1u);   // RNE
  return (unsigned short)(r >> 16);
}

// ---------------- converts ----------------
__global__ void k_conv_emb(const float4* __restrict__ src, ushort4* __restrict__ dst, int n4) {
  int i = blockIdx.x * blockDim.x + threadIdx.x;
  if (i >= n4) return;
  float4 v = src[i];
  ushort4 o;
  o.x = f2bf(v.x); o.y = f2bf(v.y); o.z = f2bf(v.z); o.w = f2bf(v.w);
  dst[i] = o;
}

// dst[j*rows + k] = bf16(src[k*cols + j]) ; dst is [cols][rows]
__global__ void k_transpose_bf(const float* __restrict__ src, unsigned short* __restrict__ dst,
                               int rows, int cols) {
  int i = blockIdx.x * blockDim.x + threadIdx.x;
  if (i >= rows * cols) return;
  int j = i / rows, k = i % rows;
  dst[i] = f2bf(src[k * cols + j]);
}

// ---------------- zoom 5: 64x256 tile, 2-barrier loop + coalesced LDS epilogue ----------------
__global__ __launch_bounds__(256) void k_h5(
    const unsigned short* __restrict__ embB,
    const unsigned short* __restrict__ W5T,
    const float* __restrict__ b5,
    const float* __restrict__ x5,
    const int* __restrict__ var_idx,
    const int* __restrict__ adjc,
    float* __restrict__ y5)
{
  __shared__ __align__(1024) unsigned char smem[8192 + 32768 + 64*4];
  unsigned char* Asm = smem;
  unsigned char* Bsm = smem + 8192;
  int* ald = (int*)(smem + 8192 + 32768);

  const int tid = threadIdx.x;
  const int l = tid & 63, w = tid >> 6;
  const int wr = w >> 1, wc = w & 1;
  const int li8 = l >> 3, pc = l & 7, l15 = l & 15, l16 = l >> 4;

  const int nt = blockIdx.x, slot = blockIdx.y;
  const int n0 = nt * 64;
  const int var = var_idx[slot];

  if (tid < 64) ald[tid] = adjc[(n0 + tid) * NH_];
  __syncthreads();

  const f32x4 fz = {0.f, 0.f, 0.f, 0.f};
  f32x4 accS[2][4], accH[2][4];
#pragma unroll
  for (int mf = 0; mf < 2; ++mf)
#pragma unroll
    for (int nf = 0; nf < 4; ++nf) { accS[mf][nf] = fz; accH[mf][nf] = fz; }

  const size_t embVarOff = (size_t)var * ((size_t)N_ * F_);

  for (int step = 0; step < 2; ++step) {
    const int k0 = step << 6;
#pragma unroll
    for (int q2 = 0; q2 < 2; ++q2) {
      const int q = w * 2 + q2;
      const int r = q * 8 + li8;
      const int lc = pc ^ (r & 7);
      const unsigned short* g = embB + embVarOff + (size_t)ald[r] * F_ + k0 + lc * 8;
      load16(g, Asm + q * 1024);
    }
#pragma unroll
    for (int q2 = 0; q2 < 8; ++q2) {
      const int q = w * 8 + q2;
      const int j = q * 8 + li8;
      const int lc = pc ^ (j & 7);
      const unsigned short* g = W5T + (size_t)j * F_ + k0 + lc * 8;
      load16(g, Bsm + q * 1024);
    }
    __syncthreads();

#pragma unroll
    for (int kf = 0; kf < 2; ++kf) {
      const int kc = kf * 4 + l16;
      bf16x8 a[2], bs[4], bh[4];
#pragma unroll
      for (int mf = 0; mf < 2; ++mf) {
        const int r = wr * 32 + mf * 16 + l15;
        a[mf] = *(const bf16x8*)(Asm + r * 128 + ((kc ^ (r & 7)) << 4));
      }
#pragma unroll
      for (int nf = 0; nf < 4; ++nf) {
        const int js = wc * 64 + nf * 16 + l15;
        bs[nf] = *(const bf16x8*)(Bsm + js * 128 + ((kc ^ (js & 7)) << 4));
        const int jh = js + 128;
        bh[nf] = *(const bf16x8*)(Bsm + jh * 128 + ((kc ^ (jh & 7)) << 4));
      }
#pragma unroll
      for (int mf = 0; mf < 2; ++mf)
#pragma unroll
        for (int nf = 0; nf < 4; ++nf) {
          accS[mf][nf] = __builtin_amdgcn_mfma_f32_16x16x32_bf16(a[mf], bs[nf], accS[mf][nf], 0, 0, 0);
          accH[mf][nf] = __builtin_amdgcn_mfma_f32_16x16x32_bf16(a[mf], bh[nf], accH[mf][nf], 0, 0, 0);
        }
    }
    __syncthreads();
  }

  // ---- coalesced epilogue via in-place LDS tile [64][128] f32 (32KB) ----
  float* LX = (float*)smem;
  const size_t row0 = ((size_t)slot * N_ + n0) * F_;
#pragma unroll
  for (int it = 0; it < 8; ++it) {
    const int g = it * 256 + tid;            // 64 rows x 32 f4
    const int row = g >> 5, c4 = g & 31;
    const int c4s = c4 ^ ((row >> 2) & 7);
    *(float4*)(LX + row * 128 + c4s * 4) =
        *(const float4*)(x5 + row0 + (size_t)row * F_ + c4 * 4);
  }
  __syncthreads();
#pragma unroll
  for (int mf = 0; mf < 2; ++mf)
#pragma unroll
    for (int nf = 0; nf < 4; ++nf) {
      const int f = wc * 64 + nf * 16 + l15;
      const float sb = b5[f];
      const float hb = b5[128 + f];
      const int c4 = f >> 2;
#pragma unroll
      for (int reg = 0; reg < 4; ++reg) {
        const int r = wr * 32 + mf * 16 + l16 * 4 + reg;
        const int fi = ((c4 ^ ((r >> 2) & 7)) << 2) + (f & 3);
        const float x = LX[r * 128 + fi];
        LX[r * 128 + fi] = x * (accS[mf][nf][reg] + sb) + (accH[mf][nf][reg] + hb);
      }
    }
  __syncthreads();
#pragma unroll
  for (int it = 0; it < 8; ++it) {
    const int g = it * 256 + tid;
    const int row = g >> 5, c4 = g & 31;
    const int c4s = c4 ^ ((row >> 2) & 7);
    *(float4*)(y5 + row0 + (size_t)row * F_ + c4 * 4) =
        *(const float4*)(LX + row * 128 + c4s * 4);
  }
}

// ---------------- zoom 6: 256x256 tile, 4-phase pipelined K-loop, deep prefetch ----------------
// 8 waves (2M x 4N). Stages for tile t+1 all issued at p0/p1 of tile t (>=3-phase slack).
// A-gather row offsets live in registers (aldv*), refreshed from LDS once per 2 K-tiles.
// Coalesced FiLM epilogue through freed LDS.
__global__ __launch_bounds__(512, 2) void k_h6(
    const unsigned short* __restrict__ embB,   // [NVARS][N][F] bf16
    const unsigned short* __restrict__ W6T,    // [1024][1152] bf16 (transposed W6)
    const float* __restrict__ b6,              // [1024]
    const float* __restrict__ x6,              // [NSLOT][NUP][F]
    const int* __restrict__ var_idx,
    const int* __restrict__ adjc,              // [N][9]
    float* __restrict__ y6)                    // [NSLOT][NUP][F]
{
  __shared__ __align__(1024) unsigned char smem[65536 + 65536 + 256*NH_*4];
  unsigned char* Asm0 = smem;                  // 2 x [256 rows x 128B], swizzled
  unsigned char* Bsm0 = smem + 65536;          // 2 x [256 rows x 128B], swizzled
  int* ald = (int*)(smem + 131072);            // 256 x 9 neighbor ids

  const int tid = threadIdx.x;
  const int l = tid & 63, w = tid >> 6;        // 8 waves
  const int wr = w >> 2, wc = w & 3;           // 2 x 4
  const int li8 = l >> 3, pc = l & 7, l15 = l & 15, l16 = l >> 4;

  // XCD-aware swizzle over flattened grid (1536 % 8 == 0 -> bijective)
  int bid = blockIdx.x + 48 * (blockIdx.y + 4 * blockIdx.z);
  bid = (bid & 7) * (1536 / 8) + (bid >> 3);
  const int nt = bid % 48;
  const int ct = (bid / 48) & 3;
  const int slot = bid / 192;

  const int n0 = nt * 256;
  const int col0 = ct * 256;
  const int var = var_idx[slot];
  const char* embBase = (const char*)(embB + (size_t)var * ((size_t)N_ * F_));
  const char* W6Tb = (const char*)W6T;

  for (int t2 = tid; t2 < 256 * NH_; t2 += 512) ald[t2] = adjc[n0 * NH_ + t2];
  __syncthreads();

  // loop-invariant per-thread constants
  const unsigned int LCC = (unsigned int)((pc ^ li8) << 4);     // swizzled chunk byte offset
  const int rA0 = (w * 2) * 8 + li8;          // A half0, q2=0 row
  const int rA1 = rA0 + 8;                    // A half0, q2=1 row
  // A-gather byte offsets (row*256) for staging-h; init h=0
  unsigned int av00 = ((unsigned int)ald[rA0 * NH_]) << 8;
  unsigned int av01 = ((unsigned int)ald[rA1 * NH_]) << 8;
  unsigned int av10 = ((unsigned int)ald[(128 + rA0) * NH_]) << 8;
  unsigned int av11 = ((unsigned int)ald[(128 + rA1) * NH_]) << 8;
  // B global byte offsets (include swizzle chunk)
  const unsigned int jb00 = (unsigned int)(col0 + rA0) * (K6_ * 2) + LCC;
  const unsigned int jb01 = (unsigned int)(col0 + rA1) * (K6_ * 2) + LCC;
  const unsigned int jb10 = (unsigned int)(col0 + 128 + rA0) * (K6_ * 2) + LCC;
  const unsigned int jb11 = (unsigned int)(col0 + 128 + rA1) * (K6_ * 2) + LCC;

#define STAGE_A(kkb, hh, bb, av_0, av_1) do {                                     \
    load16(embBase + (av_0) + (kkb) + LCC,                                        \
           Asm0 + (bb) * 32768 + (hh) * 16384 + (w * 2) * 1024);                  \
    load16(embBase + (av_1) + (kkb) + LCC,                                        \
           Asm0 + (bb) * 32768 + (hh) * 16384 + (w * 2 + 1) * 1024);              \
  } while (0)

#define STAGE_B(kb, hh, bb, jb_0, jb_1) do {                                      \
    load16(W6Tb + (jb_0) + (kb),                                                  \
           Bsm0 + (bb) * 32768 + (hh) * 16384 + (w * 2) * 1024);                  \
    load16(W6Tb + (jb_1) + (kb),                                                  \
           Bsm0 + (bb) * 32768 + (hh) * 16384 + (w * 2 + 1) * 1024);              \
  } while (0)

#define LDA(dst, mh) do {                                                         \
    _Pragma("unroll")                                                             \
    for (int mq_ = 0; mq_ < 4; ++mq_)                                             \
    _Pragma("unroll")                                                             \
    for (int kf_ = 0; kf_ < 2; ++kf_) {                                           \
      const int r_ = (mh) * 128 + wr * 64 + mq_ * 16 + l15;                       \
      const int kc_ = kf_ * 4 + l16;                                              \
      dst[mq_][kf_] = *(const bf16x8*)(Ab + r_ * 128 + ((kc_ ^ (r_ & 7)) << 4));  \
    } } while (0)

#define LDB(dst, jofs) do {                                                       \
    _Pragma("unroll")                                                             \
    for (int nf_ = 0; nf_ < 2; ++nf_)                                             \
    _Pragma("unroll")                                                             \
    for (int kf_ = 0; kf_ < 2; ++kf_) {                                           \
      const int j_ = (jofs) + wc * 32 + nf_ * 16 + l15;                           \
      const int kc_ = kf_ * 4 + l16;                                              \
      dst[nf_][kf_] = *(const bf16x8*)(Bb + j_ * 128 + ((kc_ ^ (j_ & 7)) << 4));  \
    } } while (0)

#define MM(acc, mh, af, bfr) do {                                                 \
    _Pragma("unroll")                                                             \
    for (int mq_ = 0; mq_ < 4; ++mq_)                                             \
    _Pragma("unroll")                                                             \
    for (int nf_ = 0; nf_ < 2; ++nf_)                                             \
    _Pragma("unroll")                                                             \
    for (int kf_ = 0; kf_ < 2; ++kf_)                                             \
      acc[(mh)*4+mq_][nf_] = __builtin_amdgcn_mfma_f32_16x16x32_bf16(             \
          af[mq_][kf_], bfr[nf_][kf_], acc[(mh)*4+mq_][nf_], 0, 0, 0);            \
    } while (0)

#define VMW(n)  asm volatile("s_waitcnt vmcnt(" #n ")" ::: "memory")
#define LGK0    do { asm volatile("s_waitcnt lgkmcnt(0)" ::: "memory"); \
                     __builtin_amdgcn_sched_barrier(0); } while (0)
#define BAR     __builtin_amdgcn_s_barrier()
#define PRIO1   __builtin_amdgcn_s_setprio(1)
#define PRIO0   __builtin_amdgcn_s_setprio(0)

  const f32x4 fz = {0.f, 0.f, 0.f, 0.f};
  f32x4 accS[8][2], accH[8][2];
#pragma unroll
  for (int mf = 0; mf < 8; ++mf)
#pragma unroll
    for (int nf = 0; nf < 2; ++nf) { accS[mf][nf] = fz; accH[mf][nf] = fz; }

  // prologue: stage tile 0 in consumption order A0,B0,B1,A1
  STAGE_A(0, 0, 0, av00, av01);
  STAGE_B(0, 0, 0, jb00, jb01);
  STAGE_B(0, 1, 0, jb10, jb11);
  STAGE_A(0, 1, 0, av10, av11);
  VMW(4);   // A0(0),B0(0) landed
  BAR;

#pragma unroll 1
  for (int t = 0; t < NSTEP6; ++t) {
    const unsigned char* Ab = Asm0 + (t & 1) * 32768;
    const unsigned char* Bb = Bsm0 + (t & 1) * 32768;
    const int sN = (t == NSTEP6 - 1) ? 0 : t + 1;   // stage target (wrap: junk, never read)
    const int bn = (t + 1) & 1;
    const unsigned int kkb = (unsigned int)((sN & 1) << 7);   // emb byte k-offset
    const unsigned int kb  = (unsigned int)(sN << 7);         // W6T byte k-offset

    bf16x8 a[4][2], bS[2][2], bH[2][2];

    // ---- phase 0: reads A0(t),B0(t); MFMA S half0 ----
    LDA(a, 0);
    LDB(bS, 0);
    VMW(2);                               // B1(t) landed (issued p1(t-1))
    STAGE_A(kkb, 0, bn, av00, av01);
    STAGE_B(kb, 0, bn, jb00, jb01);
    BAR; LGK0;
    PRIO1; MM(accS, 0, a, bS); PRIO0;
    BAR;

    // ---- phase 1: reads B1(t); MFMA H half0 ----
    LDB(bH, 128);
    VMW(4);                               // A1(t) landed (issued p1(t-1))
    STAGE_B(kb, 1, bn, jb10, jb11);
    STAGE_A(kkb, 1, bn, av10, av11);
    BAR; LGK0;
    PRIO1; MM(accH, 0, a, bH); PRIO0;
    BAR;

    // ---- phase 2: reads A1(t); MFMA S half1; refresh gather offsets ----
    LDA(a, 1);
    if (((t & 1) == 0) && (t < 16)) {     // next staging-h, uniform branch
      const int hn = (t >> 1) + 1;
      av00 = ((unsigned int)ald[rA0 * NH_ + hn]) << 8;
      av01 = ((unsigned int)ald[rA1 * NH_ + hn]) << 8;
      av10 = ((unsigned int)ald[(128 + rA0) * NH_ + hn]) << 8;
      av11 = ((unsigned int)ald[(128 + rA1) * NH_ + hn]) << 8;
    }
    BAR; LGK0;
    PRIO1; MM(accS, 1, a, bS); PRIO0;
    BAR;

    // ---- phase 3: all regs; MFMA H half1 ----
    VMW(4);                               // A0(t+1),B0(t+1) landed (issued p0(t))
    BAR; LGK0;
    PRIO1; MM(accH, 1, a, bH); PRIO0;
    BAR;
  }
  asm volatile("s_waitcnt vmcnt(0)" ::: "memory");
  __syncthreads();

  // ---- coalesced FiLM epilogue: per 128-row half via in-place LDS [128][128] f32 ----
  float* LX = (float*)smem;   // 64KB scratch (buffers dead)
#pragma unroll 1
  for (int mh = 0; mh < 2; ++mh) {
#pragma unroll
    for (int it = 0; it < 8; ++it) {
      const int g = it * 512 + tid;        // 128 rows x 32 f4
      const int row = g >> 5, c4 = g & 31;
      const int c4s = c4 ^ ((row >> 2) & 7);
      const int nup = 4 * (n0 + mh * 128 + row) + ct;
      *(float4*)(LX + row * 128 + c4s * 4) =
          *(const float4*)(x6 + ((size_t)slot * NUP_ + nup) * F_ + c4 * 4);
    }
    __syncthreads();
#pragma unroll
    for (int mq = 0; mq < 4; ++mq)
#pragma unroll
      for (int nf = 0; nf < 2; ++nf) {
        const int f = wc * 32 + nf * 16 + l15;
        const float sb = b6[col0 + f];
        const float hb = b6[col0 + 128 + f];
        const int c4 = f >> 2;
#pragma unroll
        for (int reg = 0; reg < 4; ++reg) {
          const int r = wr * 64 + mq * 16 + l16 * 4 + reg;   // local row in half
          const int fi = ((c4 ^ ((r >> 2) & 7)) << 2) + (f & 3);
          const float x = LX[r * 128 + fi];
          LX[r * 128 + fi] = x * (accS[mh*4+mq][nf][reg] + sb) + (accH[mh*4+mq][nf][reg] + hb);
        }
      }
    __syncthreads();
#pragma unroll
    for (int it = 0; it < 8; ++it) {
      const int g = it * 512 + tid;
      const int row = g >> 5, c4 = g & 31;
      const int c4s = c4 ^ ((row >> 2) & 7);
      const int nup = 4 * (n0 + mh * 128 + row) + ct;
      *(float4*)(y6 + ((size_t)slot * NUP_ + nup) * F_ + c4 * 4) =
          *(const float4*)(LX + row * 128 + c4s * 4);
    }
    __syncthreads();
  }

#undef STAGE_A
#undef STAGE_B
#undef LDA
#undef LDB
#undef MM
#undef VMW
#undef LGK0
#undef BAR
#undef PRIO1
#undef PRIO0
}

extern "C" void kernel_launch(void* const* d_in, const int* in_sizes, int n_in,
                              void* d_out, int out_size, void* d_ws, size_t ws_size,
                              hipStream_t stream) {
  (void)in_sizes; (void)n_in; (void)out_size; (void)ws_size;
  const float* emb = (const float*)d_in[0];
  const float* x5  = (const float*)d_in[1];
  const float* x6  = (const float*)d_in[2];
  const float* W5  = (const float*)d_in[3];
  const float* b5  = (const float*)d_in[4];
  const float* W6  = (const float*)d_in[5];
  const float* b6  = (const float*)d_in[6];
  const int* var_idx = (const int*)d_in[7];
  const int* adjc    = (const int*)d_in[8];

  float* y5 = (float*)d_out;
  float* y6 = y5 + (size_t)NSLOT_ * N_ * F_;

  unsigned short* embB = (unsigned short*)d_ws;
  unsigned short* W5T  = embB + (size_t)NVARS_ * N_ * F_;
  unsigned short* W6T  = W5T + 256 * 128;

  const int embN4 = NVARS_ * N_ * F_ / 4;
  k_conv_emb<<<(embN4 + 255) / 256, 256, 0, stream>>>((const float4*)emb, (ushort4*)embB, embN4);
  k_transpose_bf<<<(128 * 256 + 255) / 256, 256, 0, stream>>>(W5, W5T, 128, 256);
  k_transpose_bf<<<(1152 * 1024 + 255) / 256, 256, 0, stream>>>(W6, W6T, 1152, 1024);

  k_h5<<<dim3(N_ / 64, NSLOT_), 256, 0, stream>>>(embB, W5T, b5, x5, var_idx, adjc, y5);
  k_h6<<<dim3(48, 4, 8), 512, 0, stream>>>(embB, W6T, b6, x6, var_idx, adjc, y6);
}

// Round 5
// 370.217 us; speedup vs baseline: 1.2794x; 1.2794x over previous
//
#include <hip/hip_runtime.h>
#include <stdint.h>

// Problem constants
#define F_     128
#define N_     12288
#define NH_    9
#define NSLOT_ 8
#define NVARS_ 8
#define NUP_   (4*N_)
#define K6_    (NH_*F_)   // 1152

typedef __attribute__((ext_vector_type(8))) short bf16x8;
typedef __attribute__((ext_vector_type(4))) float f32x4;

typedef const __attribute__((address_space(1))) unsigned char* gp1_t;
typedef __attribute__((address_space(3))) unsigned char* lp3_t;

__device__ __forceinline__ void load16(const void* g, void* l) {
  __builtin_amdgcn_global_load_lds((gp1_t)g, (lp3_t)l, 16, 0, 0);
}

__device__ __forceinline__ unsigned short f2bf(float f) {
  union { float f; unsigned int u; } x; x.f = f;
  unsigned int u = x.u;
  unsigned int r = u + 0x7FFFu + ((u >> 16) & 1u);   // RNE
  return (unsigned short)(r >> 16);
}

// ---------------- converts ----------------
__global__ void k_conv_emb(const float4* __restrict__ src, ushort4* __restrict__ dst, int n4) {
  int i = blockIdx.x * blockDim.x + threadIdx.x;
  if (i >= n4) return;
  float4 v = src[i];
  ushort4 o;
  o.x = f2bf(v.x); o.y = f2bf(v.y); o.z = f2bf(v.z); o.w = f2bf(v.w);
  dst[i] = o;
}

// dst[j*rows + k] = bf16(src[k*cols + j]) ; dst is [cols][rows]
__global__ void k_transpose_bf(const float* __restrict__ src, unsigned short* __restrict__ dst,
                               int rows, int cols) {
  int i = blockIdx.x * blockDim.x + threadIdx.x;
  if (i >= rows * cols) return;
  int j = i / rows, k = i % rows;
  dst[i] = f2bf(src[k * cols + j]);
}

// ---------------- zoom 5: h5 = e5 @ W5 + b5 ; y5 = x5*scale + shift (var-dedup) ----------------
// block: 64 rows x 256 cols, 256 thr (4 waves: 2 wr x 2 wc), BK=64, 2 k-steps
__global__ __launch_bounds__(256) void k_h5(
    const unsigned short* __restrict__ embB,   // [NVARS][N][F] bf16
    const unsigned short* __restrict__ W5T,    // [256][128]  bf16 (transposed W5)
    const float* __restrict__ b5,              // [256]
    const float* __restrict__ x5,              // [NSLOT][N][F]
    const int* __restrict__ var_idx,           // [NSLOT]
    const int* __restrict__ adjc,              // [N][9]
    float* __restrict__ y5)                    // [NSLOT][N][F]
{
  const int slot = blockIdx.y;
  const int var = var_idx[slot];
  // var-dedup: only the first slot with this var computes; it serves all followers.
  for (int j = 0; j < NSLOT_; ++j) {
    if (j >= slot) break;
    if (var_idx[j] == var) return;            // uniform per block, before any barrier
  }
  unsigned int fmask = 0;
  for (int j = slot; j < NSLOT_; ++j)
    if (var_idx[j] == var) fmask |= 1u << j;

  __shared__ __align__(1024) unsigned char smem[8192 + 32768 + 64*4];
  unsigned char* Asm = smem;                 // 64 rows x 128 B (swizzled)
  unsigned char* Bsm = smem + 8192;          // 256 rows x 128 B (swizzled)
  int* ald = (int*)(smem + 8192 + 32768);

  const int tid = threadIdx.x;
  const int l = tid & 63, w = tid >> 6;
  const int wr = w >> 1, wc = w & 1;
  const int li8 = l >> 3, pc = l & 7, l15 = l & 15, l16 = l >> 4;

  const int nt = blockIdx.x;
  const int n0 = nt * 64;

  if (tid < 64) ald[tid] = adjc[(n0 + tid) * NH_];   // self index (col 0)
  __syncthreads();

  const f32x4 fz = {0.f, 0.f, 0.f, 0.f};
  f32x4 accS[2][4], accH[2][4];
#pragma unroll
  for (int mf = 0; mf < 2; ++mf)
#pragma unroll
    for (int nf = 0; nf < 4; ++nf) { accS[mf][nf] = fz; accH[mf][nf] = fz; }

  const size_t embVarOff = (size_t)var * ((size_t)N_ * F_);

  for (int step = 0; step < 2; ++step) {
    const int k0 = step << 6;
#pragma unroll
    for (int q2 = 0; q2 < 2; ++q2) {
      const int q = w * 2 + q2;
      const int r = q * 8 + li8;
      const int lc = pc ^ (r & 7);
      const unsigned short* g = embB + embVarOff + (size_t)ald[r] * F_ + k0 + lc * 8;
      load16(g, Asm + q * 1024);
    }
#pragma unroll
    for (int q2 = 0; q2 < 8; ++q2) {
      const int q = w * 8 + q2;
      const int j = q * 8 + li8;
      const int lc = pc ^ (j & 7);
      const unsigned short* g = W5T + (size_t)j * F_ + k0 + lc * 8;
      load16(g, Bsm + q * 1024);
    }
    __syncthreads();

#pragma unroll
    for (int kf = 0; kf < 2; ++kf) {
      const int kc = kf * 4 + l16;
      bf16x8 a[2], bs[4], bh[4];
#pragma unroll
      for (int mf = 0; mf < 2; ++mf) {
        const int r = wr * 32 + mf * 16 + l15;
        a[mf] = *(const bf16x8*)(Asm + r * 128 + ((kc ^ (r & 7)) << 4));
      }
#pragma unroll
      for (int nf = 0; nf < 4; ++nf) {
        const int js = wc * 64 + nf * 16 + l15;
        bs[nf] = *(const bf16x8*)(Bsm + js * 128 + ((kc ^ (js & 7)) << 4));
        const int jh = js + 128;
        bh[nf] = *(const bf16x8*)(Bsm + jh * 128 + ((kc ^ (jh & 7)) << 4));
      }
#pragma unroll
      for (int mf = 0; mf < 2; ++mf)
#pragma unroll
        for (int nf = 0; nf < 4; ++nf) {
          accS[mf][nf] = __builtin_amdgcn_mfma_f32_16x16x32_bf16(a[mf], bs[nf], accS[mf][nf], 0, 0, 0);
          accH[mf][nf] = __builtin_amdgcn_mfma_f32_16x16x32_bf16(a[mf], bh[nf], accH[mf][nf], 0, 0, 0);
        }
    }
    __syncthreads();
  }

  // epilogue: FiLM for every follower slot sharing this var
#pragma unroll
  for (int mf = 0; mf < 2; ++mf)
#pragma unroll
    for (int nf = 0; nf < 4; ++nf) {
      const int f = wc * 64 + nf * 16 + l15;
      const float sb = b5[f];
      const float hb = b5[128 + f];
#pragma unroll
      for (int reg = 0; reg < 4; ++reg) {
        const int r = wr * 32 + mf * 16 + l16 * 4 + reg;   // C/D: row=(l>>4)*4+reg
        const float s = accS[mf][nf][reg] + sb;
        const float h = accH[mf][nf][reg] + hb;
        const size_t base = ((size_t)(n0 + r)) * F_ + f;
        for (int j = slot; j < NSLOT_; ++j) {
          if (!(fmask & (1u << j))) continue;
          const size_t idx = (size_t)j * ((size_t)N_ * F_) + base;
          y5[idx] = x5[idx] * s + h;
        }
      }
    }
}

// ---------------- zoom 6: gathered GEMM + FiLM, round-1 structure + var-dedup ----------------
// block: 128 rows x 256 cols (one child ct), 512 thr (8 waves: 2 wr x 4 wc), BK=64, 18 steps
__global__ __launch_bounds__(512) void k_h6(
    const unsigned short* __restrict__ embB,   // [NVARS][N][F] bf16
    const unsigned short* __restrict__ W6T,    // [1024][1152] bf16 (transposed W6)
    const float* __restrict__ b6,              // [1024]
    const float* __restrict__ x6,              // [NSLOT][NUP][F]
    const int* __restrict__ var_idx,
    const int* __restrict__ adjc,              // [N][9]
    float* __restrict__ y6)                    // [NSLOT][NUP][F]
{
  const int slot = blockIdx.z;                // 0..7
  const int var = var_idx[slot];
  // var-dedup: only the first slot with this var computes; it serves all followers.
  for (int j = 0; j < NSLOT_; ++j) {
    if (j >= slot) break;
    if (var_idx[j] == var) return;            // uniform per block, before any barrier
  }
  unsigned int fmask = 0;
  for (int j = slot; j < NSLOT_; ++j)
    if (var_idx[j] == var) fmask |= 1u << j;

  __shared__ __align__(1024) unsigned char smem[16384 + 32768 + 128*NH_*4];
  unsigned char* Asm = smem;                  // 128 rows x 128 B (swizzled)
  unsigned char* Bsm = smem + 16384;          // 256 rows x 128 B (swizzled)
  int* ald = (int*)(smem + 16384 + 32768);    // 128 x 9 neighbor ids

  const int tid = threadIdx.x;
  const int l = tid & 63, w = tid >> 6;       // 8 waves
  const int wr = w >> 2, wc = w & 3;          // 2 x 4
  const int li8 = l >> 3, pc = l & 7, l15 = l & 15, l16 = l >> 4;

  const int nt = blockIdx.x;                  // 0..95
  const int ct = blockIdx.y;                  // child 0..3
  const int n0 = nt * 128;
  const int col0 = ct * 256;

  for (int t = tid; t < 128 * NH_; t += 512) ald[t] = adjc[n0 * NH_ + t];
  __syncthreads();

  const f32x4 fz = {0.f, 0.f, 0.f, 0.f};
  f32x4 accS[4][2], accH[4][2];
#pragma unroll
  for (int mf = 0; mf < 4; ++mf)
#pragma unroll
    for (int nf = 0; nf < 2; ++nf) { accS[mf][nf] = fz; accH[mf][nf] = fz; }

  const size_t embVarOff = (size_t)var * ((size_t)N_ * F_);

  for (int step = 0; step < K6_ / 64; ++step) {   // 18
    const int h = step >> 1;
    const int kk0 = (step & 1) << 6;              // offset within emb row (F=128)
    const int k0 = step << 6;                     // offset within W6T row (K=1152)

    // stage A: 16 chunks, 2 per wave (gathered rows)
#pragma unroll
    for (int q2 = 0; q2 < 2; ++q2) {
      const int q = w * 2 + q2;
      const int r = q * 8 + li8;                  // 0..127
      const int lc = pc ^ (r & 7);
      const int m = ald[r * NH_ + h];
      const unsigned short* g = embB + embVarOff + (size_t)m * F_ + kk0 + lc * 8;
      load16(g, Asm + q * 1024);
    }
    // stage B: 32 chunks, 4 per wave
#pragma unroll
    for (int q2 = 0; q2 < 4; ++q2) {
      const int q = w * 4 + q2;
      const int j = q * 8 + li8;                  // 0..255
      const int lc = pc ^ (j & 7);
      const unsigned short* g = W6T + (size_t)(col0 + j) * K6_ + k0 + lc * 8;
      load16(g, Bsm + q * 1024);
    }
    __syncthreads();

#pragma unroll
    for (int kf = 0; kf < 2; ++kf) {
      const int kc = kf * 4 + l16;
      bf16x8 a[4], bs[2], bh[2];
#pragma unroll
      for (int mf = 0; mf < 4; ++mf) {
        const int r = wr * 64 + mf * 16 + l15;
        a[mf] = *(const bf16x8*)(Asm + r * 128 + ((kc ^ (r & 7)) << 4));
      }
#pragma unroll
      for (int nf = 0; nf < 2; ++nf) {
        const int js = wc * 32 + nf * 16 + l15;
        bs[nf] = *(const bf16x8*)(Bsm + js * 128 + ((kc ^ (js & 7)) << 4));
        const int jh = js + 128;
        bh[nf] = *(const bf16x8*)(Bsm + jh * 128 + ((kc ^ (jh & 7)) << 4));
      }
#pragma unroll
      for (int mf = 0; mf < 4; ++mf)
#pragma unroll
        for (int nf = 0; nf < 2; ++nf) {
          accS[mf][nf] = __builtin_amdgcn_mfma_f32_16x16x32_bf16(a[mf], bs[nf], accS[mf][nf], 0, 0, 0);
          accH[mf][nf] = __builtin_amdgcn_mfma_f32_16x16x32_bf16(a[mf], bh[nf], accH[mf][nf], 0, 0, 0);
        }
    }
    __syncthreads();
  }

  // epilogue: FiLM for every follower slot sharing this var.
  // h6 row n reshapes to 4 children x 256; this block owns child ct.
#pragma unroll
  for (int mf = 0; mf < 4; ++mf)
#pragma unroll
    for (int nf = 0; nf < 2; ++nf) {
      const int f = wc * 32 + nf * 16 + l15;
      const float sb = b6[col0 + f];
      const float hb = b6[col0 + 128 + f];
#pragma unroll
      for (int reg = 0; reg < 4; ++reg) {
        const int r = wr * 64 + mf * 16 + l16 * 4 + reg;
        const int nup = 4 * (n0 + r) + ct;
        const float s = accS[mf][nf][reg] + sb;
        const float h = accH[mf][nf][reg] + hb;
        const size_t base = (size_t)nup * F_ + f;
        for (int j = slot; j < NSLOT_; ++j) {
          if (!(fmask & (1u << j))) continue;
          const size_t idx = (size_t)j * ((size_t)NUP_ * F_) + base;
          y6[idx] = x6[idx] * s + h;
        }
      }
    }
}

extern "C" void kernel_launch(void* const* d_in, const int* in_sizes, int n_in,
                              void* d_out, int out_size, void* d_ws, size_t ws_size,
                              hipStream_t stream) {
  (void)in_sizes; (void)n_in; (void)out_size; (void)ws_size;
  const float* emb = (const float*)d_in[0];
  const float* x5  = (const float*)d_in[1];
  const float* x6  = (const float*)d_in[2];
  const float* W5  = (const float*)d_in[3];
  const float* b5  = (const float*)d_in[4];
  const float* W6  = (const float*)d_in[5];
  const float* b6  = (const float*)d_in[6];
  const int* var_idx = (const int*)d_in[7];
  const int* adjc    = (const int*)d_in[8];

  float* y5 = (float*)d_out;
  float* y6 = y5 + (size_t)NSLOT_ * N_ * F_;

  unsigned short* embB = (unsigned short*)d_ws;                  // 12,582,912 bf16
  unsigned short* W5T  = embB + (size_t)NVARS_ * N_ * F_;        // 32,768 bf16
  unsigned short* W6T  = W5T + 256 * 128;                        // 1,179,648 bf16

  const int embN4 = NVARS_ * N_ * F_ / 4;
  k_conv_emb<<<(embN4 + 255) / 256, 256, 0, stream>>>((const float4*)emb, (ushort4*)embB, embN4);
  k_transpose_bf<<<(128 * 256 + 255) / 256, 256, 0, stream>>>(W5, W5T, 128, 256);
  k_transpose_bf<<<(1152 * 1024 + 255) / 256, 256, 0, stream>>>(W6, W6T, 1152, 1024);

  k_h5<<<dim3(N_ / 64, NSLOT_), 256, 0, stream>>>(embB, W5T, b5, x5, var_idx, adjc, y5);
  k_h6<<<dim3(N_ / 128, 4, NSLOT_), 512, 0, stream>>>(embB, W6T, b6, x6, var_idx, adjc, y6);
}

// Round 6
// 318.045 us; speedup vs baseline: 1.4892x; 1.1640x over previous
//
#include <hip/hip_runtime.h>
#include <stdint.h>

// Problem constants
#define F_     128
#define N_     12288
#define NH_    9
#define NSLOT_ 8
#define NVARS_ 8
#define NUP_   (4*N_)
#define K6_    (NH_*F_)   // 1152

typedef __attribute__((ext_vector_type(8))) short bf16x8;
typedef __attribute__((ext_vector_type(4))) float f32x4;

typedef const __attribute__((address_space(1))) unsigned char* gp1_t;
typedef __attribute__((address_space(3))) unsigned char* lp3_t;

__device__ __forceinline__ void load16(const void* g, void* l) {
  __builtin_amdgcn_global_load_lds((gp1_t)g, (lp3_t)l, 16, 0, 0);
}

__device__ __forceinline__ unsigned short f2bf(float f) {
  union { float f; unsigned int u; } x; x.f = f;
  unsigned int u = x.u;
  unsigned int r = u + 0x7FFFu + ((u >> 16) & 1u);   // RNE
  return (unsigned short)(r >> 16);
}

// ---------------- converts ----------------
__global__ void k_conv_emb(const float4* __restrict__ src, ushort4* __restrict__ dst, int n4) {
  int i = blockIdx.x * blockDim.x + threadIdx.x;
  if (i >= n4) return;
  float4 v = src[i];
  ushort4 o;
  o.x = f2bf(v.x); o.y = f2bf(v.y); o.z = f2bf(v.z); o.w = f2bf(v.w);
  dst[i] = o;
}

// dst[j*rows + k] = bf16(src[k*cols + j]) ; dst is [cols][rows]
__global__ void k_transpose_bf(const float* __restrict__ src, unsigned short* __restrict__ dst,
                               int rows, int cols) {
  int i = blockIdx.x * blockDim.x + threadIdx.x;
  if (i >= rows * cols) return;
  int j = i / rows, k = i % rows;
  dst[i] = f2bf(src[k * cols + j]);
}

// ---------------- zoom 5: h5 = e5 @ W5 + b5 ; y5 = x5*scale + shift (var-dedup) ----------------
// block: 64 rows x 256 cols, 256 thr (4 waves: 2 wr x 2 wc), BK=64, 2 k-steps
__global__ __launch_bounds__(256) void k_h5(
    const unsigned short* __restrict__ embB,   // [NVARS][N][F] bf16
    const unsigned short* __restrict__ W5T,    // [256][128]  bf16 (transposed W5)
    const float* __restrict__ b5,              // [256]
    const float* __restrict__ x5,              // [NSLOT][N][F]
    const int* __restrict__ var_idx,           // [NSLOT]
    const int* __restrict__ adjc,              // [N][9]
    float* __restrict__ y5)                    // [NSLOT][N][F]
{
  const int slot = blockIdx.y;
  const int var = var_idx[slot];
  // var-dedup: only the first slot with this var computes; it serves all followers.
  for (int j = 0; j < NSLOT_; ++j) {
    if (j >= slot) break;
    if (var_idx[j] == var) return;            // uniform per block, before any barrier
  }
  unsigned int fmask = 0;
  for (int j = slot; j < NSLOT_; ++j)
    if (var_idx[j] == var) fmask |= 1u << j;

  __shared__ __align__(1024) unsigned char smem[8192 + 32768 + 64*4];
  unsigned char* Asm = smem;                 // 64 rows x 128 B (swizzled)
  unsigned char* Bsm = smem + 8192;          // 256 rows x 128 B (swizzled)
  int* ald = (int*)(smem + 8192 + 32768);

  const int tid = threadIdx.x;
  const int l = tid & 63, w = tid >> 6;
  const int wr = w >> 1, wc = w & 1;
  const int li8 = l >> 3, pc = l & 7, l15 = l & 15, l16 = l >> 4;

  const int nt = blockIdx.x;
  const int n0 = nt * 64;

  if (tid < 64) ald[tid] = adjc[(n0 + tid) * NH_];   // self index (col 0)
  __syncthreads();

  const f32x4 fz = {0.f, 0.f, 0.f, 0.f};
  f32x4 accS[2][4], accH[2][4];
#pragma unroll
  for (int mf = 0; mf < 2; ++mf)
#pragma unroll
    for (int nf = 0; nf < 4; ++nf) { accS[mf][nf] = fz; accH[mf][nf] = fz; }

  const size_t embVarOff = (size_t)var * ((size_t)N_ * F_);

  for (int step = 0; step < 2; ++step) {
    const int k0 = step << 6;
#pragma unroll
    for (int q2 = 0; q2 < 2; ++q2) {
      const int q = w * 2 + q2;
      const int r = q * 8 + li8;
      const int lc = pc ^ (r & 7);
      const unsigned short* g = embB + embVarOff + (size_t)ald[r] * F_ + k0 + lc * 8;
      load16(g, Asm + q * 1024);
    }
#pragma unroll
    for (int q2 = 0; q2 < 8; ++q2) {
      const int q = w * 8 + q2;
      const int j = q * 8 + li8;
      const int lc = pc ^ (j & 7);
      const unsigned short* g = W5T + (size_t)j * F_ + k0 + lc * 8;
      load16(g, Bsm + q * 1024);
    }
    __syncthreads();

#pragma unroll
    for (int kf = 0; kf < 2; ++kf) {
      const int kc = kf * 4 + l16;
      bf16x8 a[2], bs[4], bh[4];
#pragma unroll
      for (int mf = 0; mf < 2; ++mf) {
        const int r = wr * 32 + mf * 16 + l15;
        a[mf] = *(const bf16x8*)(Asm + r * 128 + ((kc ^ (r & 7)) << 4));
      }
#pragma unroll
      for (int nf = 0; nf < 4; ++nf) {
        const int js = wc * 64 + nf * 16 + l15;
        bs[nf] = *(const bf16x8*)(Bsm + js * 128 + ((kc ^ (js & 7)) << 4));
        const int jh = js + 128;
        bh[nf] = *(const bf16x8*)(Bsm + jh * 128 + ((kc ^ (jh & 7)) << 4));
      }
#pragma unroll
      for (int mf = 0; mf < 2; ++mf)
#pragma unroll
        for (int nf = 0; nf < 4; ++nf) {
          accS[mf][nf] = __builtin_amdgcn_mfma_f32_16x16x32_bf16(a[mf], bs[nf], accS[mf][nf], 0, 0, 0);
          accH[mf][nf] = __builtin_amdgcn_mfma_f32_16x16x32_bf16(a[mf], bh[nf], accH[mf][nf], 0, 0, 0);
        }
    }
    __syncthreads();
  }

  // epilogue: slot loop OUTERMOST; each pass has round-1's coalesced access pattern
  for (int j = slot; j < NSLOT_; ++j) {
    if (!(fmask & (1u << j))) continue;
    const size_t sbase = (size_t)j * ((size_t)N_ * F_);
#pragma unroll
    for (int mf = 0; mf < 2; ++mf)
#pragma unroll
      for (int nf = 0; nf < 4; ++nf) {
        const int f = wc * 64 + nf * 16 + l15;
        const float sb = b5[f];
        const float hb = b5[128 + f];
#pragma unroll
        for (int reg = 0; reg < 4; ++reg) {
          const int r = wr * 32 + mf * 16 + l16 * 4 + reg;   // C/D: row=(l>>4)*4+reg
          const size_t idx = sbase + ((size_t)(n0 + r)) * F_ + f;
          y5[idx] = x5[idx] * (accS[mf][nf][reg] + sb) + (accH[mf][nf][reg] + hb);
        }
      }
  }
}

// ---------------- zoom 6: gathered GEMM + FiLM, round-1 structure + var-dedup ----------------
// block: 128 rows x 256 cols (one child ct), 512 thr (8 waves: 2 wr x 4 wc), BK=64, 18 steps
__global__ __launch_bounds__(512) void k_h6(
    const unsigned short* __restrict__ embB,   // [NVARS][N][F] bf16
    const unsigned short* __restrict__ W6T,    // [1024][1152] bf16 (transposed W6)
    const float* __restrict__ b6,              // [1024]
    const float* __restrict__ x6,              // [NSLOT][NUP][F]
    const int* __restrict__ var_idx,
    const int* __restrict__ adjc,              // [N][9]
    float* __restrict__ y6)                    // [NSLOT][NUP][F]
{
  const int slot = blockIdx.z;                // 0..7
  const int var = var_idx[slot];
  // var-dedup: only the first slot with this var computes; it serves all followers.
  for (int j = 0; j < NSLOT_; ++j) {
    if (j >= slot) break;
    if (var_idx[j] == var) return;            // uniform per block, before any barrier
  }
  unsigned int fmask = 0;
  for (int j = slot; j < NSLOT_; ++j)
    if (var_idx[j] == var) fmask |= 1u << j;

  __shared__ __align__(1024) unsigned char smem[16384 + 32768 + 128*NH_*4];
  unsigned char* Asm = smem;                  // 128 rows x 128 B (swizzled)
  unsigned char* Bsm = smem + 16384;          // 256 rows x 128 B (swizzled)
  int* ald = (int*)(smem + 16384 + 32768);    // 128 x 9 neighbor ids

  const int tid = threadIdx.x;
  const int l = tid & 63, w = tid >> 6;       // 8 waves
  const int wr = w >> 2, wc = w & 3;          // 2 x 4
  const int li8 = l >> 3, pc = l & 7, l15 = l & 15, l16 = l >> 4;

  const int nt = blockIdx.x;                  // 0..95
  const int ct = blockIdx.y;                  // child 0..3
  const int n0 = nt * 128;
  const int col0 = ct * 256;

  for (int t = tid; t < 128 * NH_; t += 512) ald[t] = adjc[n0 * NH_ + t];
  __syncthreads();

  const f32x4 fz = {0.f, 0.f, 0.f, 0.f};
  f32x4 accS[4][2], accH[4][2];
#pragma unroll
  for (int mf = 0; mf < 4; ++mf)
#pragma unroll
    for (int nf = 0; nf < 2; ++nf) { accS[mf][nf] = fz; accH[mf][nf] = fz; }

  const size_t embVarOff = (size_t)var * ((size_t)N_ * F_);

  for (int step = 0; step < K6_ / 64; ++step) {   // 18
    const int h = step >> 1;
    const int kk0 = (step & 1) << 6;              // offset within emb row (F=128)
    const int k0 = step << 6;                     // offset within W6T row (K=1152)

    // stage A: 16 chunks, 2 per wave (gathered rows)
#pragma unroll
    for (int q2 = 0; q2 < 2; ++q2) {
      const int q = w * 2 + q2;
      const int r = q * 8 + li8;                  // 0..127
      const int lc = pc ^ (r & 7);
      const int m = ald[r * NH_ + h];
      const unsigned short* g = embB + embVarOff + (size_t)m * F_ + kk0 + lc * 8;
      load16(g, Asm + q * 1024);
    }
    // stage B: 32 chunks, 4 per wave
#pragma unroll
    for (int q2 = 0; q2 < 4; ++q2) {
      const int q = w * 4 + q2;
      const int j = q * 8 + li8;                  // 0..255
      const int lc = pc ^ (j & 7);
      const unsigned short* g = W6T + (size_t)(col0 + j) * K6_ + k0 + lc * 8;
      load16(g, Bsm + q * 1024);
    }
    __syncthreads();

#pragma unroll
    for (int kf = 0; kf < 2; ++kf) {
      const int kc = kf * 4 + l16;
      bf16x8 a[4], bs[2], bh[2];
#pragma unroll
      for (int mf = 0; mf < 4; ++mf) {
        const int r = wr * 64 + mf * 16 + l15;
        a[mf] = *(const bf16x8*)(Asm + r * 128 + ((kc ^ (r & 7)) << 4));
      }
#pragma unroll
      for (int nf = 0; nf < 2; ++nf) {
        const int js = wc * 32 + nf * 16 + l15;
        bs[nf] = *(const bf16x8*)(Bsm + js * 128 + ((kc ^ (js & 7)) << 4));
        const int jh = js + 128;
        bh[nf] = *(const bf16x8*)(Bsm + jh * 128 + ((kc ^ (jh & 7)) << 4));
      }
#pragma unroll
      for (int mf = 0; mf < 4; ++mf)
#pragma unroll
        for (int nf = 0; nf < 2; ++nf) {
          accS[mf][nf] = __builtin_amdgcn_mfma_f32_16x16x32_bf16(a[mf], bs[nf], accS[mf][nf], 0, 0, 0);
          accH[mf][nf] = __builtin_amdgcn_mfma_f32_16x16x32_bf16(a[mf], bh[nf], accH[mf][nf], 0, 0, 0);
        }
    }
    __syncthreads();
  }

  // epilogue: slot loop OUTERMOST; each pass has round-1's coalesced access pattern.
  // h6 row n reshapes to 4 children x 256; this block owns child ct.
  for (int j = slot; j < NSLOT_; ++j) {
    if (!(fmask & (1u << j))) continue;
    const size_t sbase = (size_t)j * ((size_t)NUP_ * F_);
#pragma unroll
    for (int mf = 0; mf < 4; ++mf)
#pragma unroll
      for (int nf = 0; nf < 2; ++nf) {
        const int f = wc * 32 + nf * 16 + l15;
        const float sb = b6[col0 + f];
        const float hb = b6[col0 + 128 + f];
#pragma unroll
        for (int reg = 0; reg < 4; ++reg) {
          const int r = wr * 64 + mf * 16 + l16 * 4 + reg;
          const int nup = 4 * (n0 + r) + ct;
          const size_t idx = sbase + (size_t)nup * F_ + f;
          y6[idx] = x6[idx] * (accS[mf][nf][reg] + sb) + (accH[mf][nf][reg] + hb);
        }
      }
  }
}

extern "C" void kernel_launch(void* const* d_in, const int* in_sizes, int n_in,
                              void* d_out, int out_size, void* d_ws, size_t ws_size,
                              hipStream_t stream) {
  (void)in_sizes; (void)n_in; (void)out_size; (void)ws_size;
  const float* emb = (const float*)d_in[0];
  const float* x5  = (const float*)d_in[1];
  const float* x6  = (const float*)d_in[2];
  const float* W5  = (const float*)d_in[3];
  const float* b5  = (const float*)d_in[4];
  const float* W6  = (const float*)d_in[5];
  const float* b6  = (const float*)d_in[6];
  const int* var_idx = (const int*)d_in[7];
  const int* adjc    = (const int*)d_in[8];

  float* y5 = (float*)d_out;
  float* y6 = y5 + (size_t)NSLOT_ * N_ * F_;

  unsigned short* embB = (unsigned short*)d_ws;                  // 12,582,912 bf16
  unsigned short* W5T  = embB + (size_t)NVARS_ * N_ * F_;        // 32,768 bf16
  unsigned short* W6T  = W5T + 256 * 128;                        // 1,179,648 bf16

  const int embN4 = NVARS_ * N_ * F_ / 4;
  k_conv_emb<<<(embN4 + 255) / 256, 256, 0, stream>>>((const float4*)emb, (ushort4*)embB, embN4);
  k_transpose_bf<<<(128 * 256 + 255) / 256, 256, 0, stream>>>(W5, W5T, 128, 256);
  k_transpose_bf<<<(1152 * 1024 + 255) / 256, 256, 0, stream>>>(W6, W6T, 1152, 1024);

  k_h5<<<dim3(N_ / 64, NSLOT_), 256, 0, stream>>>(embB, W5T, b5, x5, var_idx, adjc, y5);
  k_h6<<<dim3(N_ / 128, 4, NSLOT_), 512, 0, stream>>>(embB, W6T, b6, x6, var_idx, adjc, y6);
}